// Round 6
// baseline (149.054 us; speedup 1.0000x reference)
//
#include <hip/hip_runtime.h>
#include <math.h>

#define T_    2048
#define BTOK  4096   // B * T
#define KB    64
#define NSLOT 72     // sum over 16 strips of ceil((s+1)/2)

namespace {
constexpr int GRADE[16] = {0,1,1,1,1,2,2,2,2,2,2,3,3,3,3,4};
constexpr int AUGK[16]  = {-1,5,-1,-1,-1,6,6,6,-1,-1,-1,7,7,7,-1,8};
constexpr int AUGS[16]  = { 0,0, 0, 0, 0,2,3,4, 0, 0, 0,8,9,10,0,14};
constexpr float FINNER[16] = {1.f,0.f,1.f,1.f,1.f,0.f,0.f,0.f,1.f,1.f,1.f,0.f,0.f,0.f,1.f,0.f};
}

__device__ __forceinline__ float gelu_f(float v){
  return 0.5f*v*(1.f + erff(v*0.70710678118654752f));
}

__device__ __forceinline__ int rsign_d(int a, int b){
  int s=0; a>>=1; while(a){ s += __popc(a&b); a>>=1; } return (s&1) ? -1 : 1;
}

// triangular slot base for strip s (s=0..15): c(s)=(s+2)>>1
__device__ __forceinline__ int strip_base(int s){
  int k=s>>1;
  return (s&1)? (k+1)*(k+1) : k*k+k;
}

// ---- K_A: embed + in-linear + norm + QKV projections + pack --------------
// 64 threads = 4 tokens x 16 lanes (8 channels x 2 input-halves).
__global__ void __launch_bounds__(64) k_in(
    const float* __restrict__ x,
    const float* __restrict__ w_in_mv, const float* __restrict__ b_in_mv,
    const float* __restrict__ w_in_m2s, const float* __restrict__ b_in_s,
    const float* __restrict__ w_mv, const float* __restrict__ w_s2mv,
    const float* __restrict__ w_m2s, const float* __restrict__ w_s2s,
    float* __restrict__ h_mv, float* __restrict__ h_s,
    float* __restrict__ qp_, float* __restrict__ kp_, float* __restrict__ vp_)
{
  __shared__ float NS[4*152];   // per token: n_mv 128 + n_s 24
  int tid=threadIdx.x, tl=tid>>4, ln=tid&15;
  int o=ln&7, ih=ln>>3;
  int tt=blockIdx.x*4+tl;
  int b=tt>>11, t=tt&(T_-1);
  const float* xp = x+(size_t)tt*6;
  float mv[16];
  #pragma unroll
  for(int p=0;p<16;p++) mv[p]=0.f;
  mv[0]=1.f; mv[14]=1.f;
  mv[13]=-xp[0]; mv[12]=xp[1]; mv[11]=-xp[2];
  mv[5]=0.5f*xp[3]; mv[6]=0.5f*xp[4]; mv[7]=0.5f*xp[5];

  const float* wo=w_in_mv+o*9;
  float h[16]; float sq=0.f;
  #pragma unroll
  for(int p=0;p<16;p++){
    float v=wo[GRADE[p]]*mv[p];
    if(AUGK[p]>=0) v+=wo[AUGK[p]]*mv[AUGS[p]];
    if(p==0) v+=b_in_mv[o];
    h[p]=v; sq+=FINNER[p]*v*v;
  }
  sq+=__shfl_xor(sq,1); sq+=__shfl_xor(sq,2); sq+=__shfl_xor(sq,4);
  float dmv=rsqrtf(sq*0.125f+0.01f);
  float hs[3]; float ssq=0.f;
  #pragma unroll
  for(int jj=0;jj<3;jj++){ float v=w_in_m2s[o*3+jj]+b_in_s[o*3+jj]; hs[jj]=v; ssq+=v*v; }
  ssq+=__shfl_xor(ssq,1); ssq+=__shfl_xor(ssq,2); ssq+=__shfl_xor(ssq,4);
  float dss=rsqrtf(ssq*(1.f/24.f)+0.01f);

  float* ns=&NS[tl*152];
  if(ih==0){
    float4* hg=(float4*)(h_mv+(size_t)tt*128+o*16);
    hg[0]=make_float4(h[0],h[1],h[2],h[3]);
    hg[1]=make_float4(h[4],h[5],h[6],h[7]);
    hg[2]=make_float4(h[8],h[9],h[10],h[11]);
    hg[3]=make_float4(h[12],h[13],h[14],h[15]);
    #pragma unroll
    for(int jj=0;jj<3;jj++) h_s[(size_t)tt*24+o*3+jj]=hs[jj];
    #pragma unroll
    for(int p=0;p<16;p++) ns[o*16+p]=h[p]*dmv;
    #pragma unroll
    for(int jj=0;jj<3;jj++) ns[128+o*3+jj]=hs[jj]*dss;
  }
  __syncthreads();

  float yq[16],yk[16],yv[16];
  #pragma unroll
  for(int p=0;p<16;p++){ yq[p]=0.f; yk[p]=0.f; yv[p]=0.f; }
  float nx0p[4];
  const float* wq=w_mv+o*72;
  #pragma unroll
  for(int ii=0;ii<4;ii++){
    int i=ih*4+ii;
    float xi[16];
    const float4* xs4=(const float4*)&ns[i*16];
    #pragma unroll
    for(int r4=0;r4<4;r4++){ float4 v=xs4[r4]; xi[r4*4]=v.x; xi[r4*4+1]=v.y; xi[r4*4+2]=v.z; xi[r4*4+3]=v.w; }
    nx0p[ii]=xi[0];
    const float* aq=wq+i*9; const float* ak=aq+576; const float* av=aq+1152;
    #pragma unroll
    for(int p=0;p<16;p++){
      float bb=xi[p];
      yq[p]+=aq[GRADE[p]]*bb; yk[p]+=ak[GRADE[p]]*bb; yv[p]+=av[GRADE[p]]*bb;
      if(AUGK[p]>=0){
        float au=xi[AUGS[p]];
        yq[p]+=aq[AUGK[p]]*au; yk[p]+=ak[AUGK[p]]*au; yv[p]+=av[AUGK[p]]*au;
      }
    }
  }
  float eq=0.f,ek=0.f,ev=0.f;
  float sq3[3]={0,0,0}, sk3[3]={0,0,0}, sv3[3]={0,0,0};
  for(int j=ih*12;j<ih*12+12;j++){
    float s=ns[128+j];
    eq+=w_s2mv[o*24+j]*s; ek+=w_s2mv[192+o*24+j]*s; ev+=w_s2mv[384+o*24+j]*s;
    #pragma unroll
    for(int jj=0;jj<3;jj++){
      int d=o*3+jj;
      sq3[jj]+=w_s2s[d*24+j]*s;
      sk3[jj]+=w_s2s[576+d*24+j]*s;
      sv3[jj]+=w_s2s[1152+d*24+j]*s;
    }
  }
  #pragma unroll
  for(int ii=0;ii<4;ii++){
    int i=ih*4+ii;
    #pragma unroll
    for(int jj=0;jj<3;jj++){
      int d=o*3+jj;
      sq3[jj]+=w_m2s[d*8+i]*nx0p[ii];
      sk3[jj]+=w_m2s[192+d*8+i]*nx0p[ii];
      sv3[jj]+=w_m2s[384+d*8+i]*nx0p[ii];
    }
  }
  yq[0]+=eq; yk[0]+=ek; yv[0]+=ev;
  #pragma unroll
  for(int p=0;p<16;p++){
    yq[p]+=__shfl_xor(yq[p],8);
    yk[p]+=__shfl_xor(yk[p],8);
    yv[p]+=__shfl_xor(yv[p],8);
  }
  #pragma unroll
  for(int jj=0;jj<3;jj++){
    sq3[jj]+=__shfl_xor(sq3[jj],8);
    sk3[jj]+=__shfl_xor(sk3[jj],8);
    sv3[jj]+=__shfl_xor(sv3[jj],8);
  }

  const float scale = 0.3015113445777636f;  // 1/sqrt(11)
  size_t rb=((size_t)(b*8+o)*T_+t);
  if(ih==0){
    float4* qr=(float4*)(qp_+rb*12);
    qr[0]=make_float4(yq[0]*scale, yq[2]*scale, yq[3]*scale, yq[4]*scale);
    qr[1]=make_float4(yq[8]*scale, yq[9]*scale, yq[10]*scale, yq[14]*scale);
    qr[2]=make_float4(sq3[0]*scale, sq3[1]*scale, sq3[2]*scale, 0.f);
    float4* vr=(float4*)(vp_+rb*20);
    vr[0]=make_float4(yv[0],yv[1],yv[2],yv[3]);
    vr[1]=make_float4(yv[4],yv[5],yv[6],yv[7]);
    vr[2]=make_float4(yv[8],yv[9],yv[10],yv[11]);
  } else {
    float4* kr=(float4*)(kp_+rb*12);
    kr[0]=make_float4(yk[0],yk[2],yk[3],yk[4]);
    kr[1]=make_float4(yk[8],yk[9],yk[10],yk[14]);
    kr[2]=make_float4(sk3[0],sk3[1],sk3[2],0.f);
    float4* vr=(float4*)(vp_+rb*20);
    vr[3]=make_float4(yv[12],yv[13],yv[14],yv[15]);
    vr[4]=make_float4(sv3[0],sv3[1],sv3[2],0.f);
  }
}

// ---- K_B: attention, no-max softmax, balanced flash-split ----------------
// 256 thr = 32 q-threads x 8 key-lanes; 4 queries/thread (128-query strip).
// 1152 blocks = 16 bh x 72 slots; each slot <= 4 key-tiles. Heavy-first.
__global__ void __launch_bounds__(256,3) k_attn(
    const float* __restrict__ qp_, const float* __restrict__ kp_,
    const float* __restrict__ vp_,
    float* __restrict__ part)
{
  __shared__ float Kt[KB*12];
  __shared__ float Vt[KB*20];
  int tid=threadIdx.x; int qi=tid>>3, ki=tid&7;
  int j=blockIdx.x;
  int bh=j&15;
  int z=NSLOT-1-(j>>4);          // ascending slot id; j ordered heavy-first
  // decode z -> (strip s, split sp): c(s)=(s+2)>>1
  int s=0, bse=0;
  while (bse + ((s+2)>>1) <= z){ bse += (s+2)>>1; s++; }
  int sp = z - bse;
  int c  = (s+2)>>1;
  int ntiles = 2*(s+1);
  int t0 = sp*ntiles/c, t1 = (sp+1)*ntiles/c;
  int q0 = s*128;

  float qp[4][12];
  int kend[4];
  #pragma unroll
  for(int w=0;w<4;w++){
    int q=q0+qi+32*w;
    kend[w]=(q&~15)+16;
    const float4* p4=(const float4*)(qp_+((size_t)bh*T_+q)*12);
    #pragma unroll
    for(int i=0;i<3;i++){ float4 v=p4[i];
      qp[w][i*4]=v.x; qp[w][i*4+1]=v.y; qp[w][i*4+2]=v.z; qp[w][i*4+3]=v.w; }
  }

  float acc[4][20];
  #pragma unroll
  for(int w=0;w<4;w++)
    #pragma unroll
    for(int p=0;p<20;p++) acc[w][p]=0.f;

  const float4* gk=(const float4*)(kp_+(size_t)bh*T_*12);
  const float4* gv=(const float4*)(vp_+(size_t)bh*T_*20);

  for(int tile=t0; tile<t1; ++tile){
    int s0=tile*KB;
    int i1=tid, i2=tid+256;
    if(i1<192) ((float4*)Kt)[i1]=gk[s0*3+i1];
    else       ((float4*)Vt)[i1-192]=gv[s0*5+(i1-192)];
    ((float4*)Vt)[i2-192]=gv[s0*5+(i2-192)];
    __syncthreads();
    #pragma unroll 2
    for(int it=0; it<8; ++it){
      int r=ki+it*8;
      int skey=s0+r;
      const float4* K4=(const float4*)&Kt[r*12];
      float4 k0=K4[0],k1=K4[1],k2=K4[2];
      float cc[4];
      #pragma unroll
      for(int w=0;w<4;w++){
        float d = qp[w][0]*k0.x+qp[w][1]*k0.y+qp[w][2]*k0.z+qp[w][3]*k0.w
                + qp[w][4]*k1.x+qp[w][5]*k1.y+qp[w][6]*k1.z+qp[w][7]*k1.w
                + qp[w][8]*k2.x+qp[w][9]*k2.y+qp[w][10]*k2.z;
        cc[w]=(skey<kend[w])? __expf(d) : 0.f;
      }
      const float4* V4=(const float4*)&Vt[r*20];
      float4 v0=V4[0],v1=V4[1],v2=V4[2],v3=V4[3],v4=V4[4];
      #pragma unroll
      for(int w=0;w<4;w++){
        float cw=cc[w];
        acc[w][0]+=cw*v0.x; acc[w][1]+=cw*v0.y; acc[w][2]+=cw*v0.z; acc[w][3]+=cw*v0.w;
        acc[w][4]+=cw*v1.x; acc[w][5]+=cw*v1.y; acc[w][6]+=cw*v1.z; acc[w][7]+=cw*v1.w;
        acc[w][8]+=cw*v2.x; acc[w][9]+=cw*v2.y; acc[w][10]+=cw*v2.z; acc[w][11]+=cw*v2.w;
        acc[w][12]+=cw*v3.x; acc[w][13]+=cw*v3.y; acc[w][14]+=cw*v3.z; acc[w][15]+=cw*v3.w;
        acc[w][16]+=cw;
        acc[w][17]+=cw*v4.x; acc[w][18]+=cw*v4.y; acc[w][19]+=cw*v4.z;
      }
    }
    __syncthreads();
  }

  // butterfly sum across 8 key-lanes (pure adds)
  #pragma unroll
  for(int mk=1; mk<8; mk<<=1){
    #pragma unroll
    for(int w=0;w<4;w++)
      #pragma unroll
      for(int p=0;p<20;p++) acc[w][p]+=__shfl_xor(acc[w][p],mk);
  }

  if(ki==0){
    #pragma unroll
    for(int w=0;w<4;w++){
      float* pr = part + ((size_t)(bh*NSLOT + z)*128 + qi + 32*w)*20;
      float4* p4=(float4*)pr;
      p4[0]=make_float4(acc[w][0],acc[w][1],acc[w][2],acc[w][3]);
      p4[1]=make_float4(acc[w][4],acc[w][5],acc[w][6],acc[w][7]);
      p4[2]=make_float4(acc[w][8],acc[w][9],acc[w][10],acc[w][11]);
      p4[3]=make_float4(acc[w][12],acc[w][13],acc[w][14],acc[w][15]);
      p4[4]=make_float4(acc[w][16],acc[w][17],acc[w][18],acc[w][19]);
    }
  }
}

// ---- K_C: combine partials + ao + norm + m1 + GP/join + m2 + out ---------
__global__ void __launch_bounds__(64) k_tail(
    const float* __restrict__ part,
    const float* __restrict__ w_ao_mv, const float* __restrict__ w_ao_s2mv,
    const float* __restrict__ w_ao_m2s, const float* __restrict__ w_ao_s2s,
    const float* __restrict__ b_ao_mv, const float* __restrict__ b_ao_s,
    const float* __restrict__ h_mv, const float* __restrict__ h_s,
    const float* __restrict__ w_m1_mv, const float* __restrict__ w_m1_s2mv,
    const float* __restrict__ w_m1_m2s, const float* __restrict__ w_m1_s2s,
    const float* __restrict__ b_m1_mv, const float* __restrict__ b_m1_s,
    const float* __restrict__ w_m2_mv, const float* __restrict__ w_m2_s2mv,
    const float* __restrict__ b_m2_mv,
    const float* __restrict__ w_out_mv,
    float* __restrict__ out)
{
  __shared__ int   GPI[256]; __shared__ float GPS[256];
  __shared__ int   JNI[256]; __shared__ float JNS[256];
  __shared__ float OS[4*152];
  __shared__ float NS[4*152];
  __shared__ float U[4*264];
  __shared__ float G[4*136];
  __shared__ float GSm[4*24];
  int tid=threadIdx.x, tl=tid>>4, ln=tid&15;
  int o=ln&7, ih=ln>>3;
  int tt=blockIdx.x*4+tl;

  { // build tables (threads 0..31)
    const int mask_of[16]={0,1,2,4,8,3,5,9,6,10,12,7,11,13,14,15};
    const int idx_of[16] ={0,1,2,5,3,6,8,11,4,7,9,12,10,13,14,15};
    if (tid<16){
      int k=tid, km=mask_of[k], slotn=0;
      for(int i=0;i<16;i++){
        int im=mask_of[i], jm=im^km;
        if(im & jm & 1) continue;
        GPI[k*16+slotn]=i|(idx_of[jm]<<4);
        GPS[k*16+slotn]=(float)rsign_d(im,jm);
        slotn++;
      }
      for(;slotn<16;slotn++){ GPI[k*16+slotn]=0; GPS[k*16+slotn]=0.f; }
    } else if (tid<32){
      int p=tid-16, pm=mask_of[p], rest=15&~pm, slotn=0;
      for(int u=0;u<16;u++){
        if(u & ~rest) continue;
        int am=pm|u, bm=pm|(rest&~u);
        float s=(float)( rsign_d(pm,15&~pm)*rsign_d(15&~am,15&~bm)
                        *rsign_d(am,15&~am)*rsign_d(bm,15&~bm) );
        JNI[p*16+slotn]=idx_of[am]|(idx_of[bm]<<4);
        JNS[p*16+slotn]=s;
        slotn++;
      }
      for(;slotn<16;slotn++){ JNI[p*16+slotn]=0; JNS[p*16+slotn]=0.f; }
    }
  }

  // combine attention partials: lane = (head h, comp-half)
  {
    int b=tt>>11, t=tt&(T_-1);
    int strip=t>>7, qi=t&127;
    int h=ln>>1, half=ln&1;
    int nsp=(strip+2)>>1;
    int kk=strip>>1;
    int rbase=(strip&1)? (kk+1)*(kk+1) : kk*kk+kk;
    const float* pb = part + ((size_t)((b*8+h)*NSLOT+rbase)*128 + qi)*20;
    float am[8]={0,0,0,0,0,0,0,0};
    float lv=0.f, s0=0.f, s1=0.f, s2=0.f;
    for(int spp=0; spp<nsp; ++spp){
      const float4* p4=(const float4*)(pb + (size_t)spp*128*20);
      float4 a=p4[half*2], b4=p4[half*2+1], meta=p4[4];
      am[0]+=a.x; am[1]+=a.y; am[2]+=a.z; am[3]+=a.w;
      am[4]+=b4.x; am[5]+=b4.y; am[6]+=b4.z; am[7]+=b4.w;
      lv+=meta.x; s0+=meta.y; s1+=meta.z; s2+=meta.w;
    }
    float inv=1.f/lv;
    float* os=&OS[tl*152];
    #pragma unroll
    for(int p=0;p<8;p++) os[h*16+half*8+p]=am[p]*inv;
    if(half==1){ os[128+h*3]=s0*inv; os[128+h*3+1]=s1*inv; os[128+h*3+2]=s2*inv; }
  }
  __syncthreads();

  const float* os=&OS[tl*152];
  float xh[4][16];
  #pragma unroll
  for(int ii=0;ii<4;ii++){
    #pragma unroll
    for(int p=0;p<16;p++) xh[ii][p]=os[(ih*4+ii)*16+p];
  }
  float xs[24];
  #pragma unroll
  for(int jj=0;jj<24;jj++) xs[jj]=os[128+jj];

  // ao: channel o, partial over i-half and j-half
  float y[16];
  #pragma unroll
  for(int p=0;p<16;p++) y[p]=0.f;
  #pragma unroll
  for(int ii=0;ii<4;ii++){
    const float* wi=w_ao_mv+o*72+(ih*4+ii)*9;
    #pragma unroll
    for(int p=0;p<16;p++){
      y[p]+=wi[GRADE[p]]*xh[ii][p];
      if(AUGK[p]>=0) y[p]+=wi[AUGK[p]]*xh[ii][AUGS[p]];
    }
  }
  float e=(ih==0)? b_ao_mv[o] : 0.f;
  for(int j2=ih*12;j2<ih*12+12;j2++) e+=w_ao_s2mv[o*24+j2]*xs[j2];
  y[0]+=e;
  float a3[3];
  #pragma unroll
  for(int jj=0;jj<3;jj++) a3[jj]=(ih==0)? b_ao_s[o*3+jj] : 0.f;
  #pragma unroll
  for(int ii=0;ii<4;ii++){
    #pragma unroll
    for(int jj=0;jj<3;jj++) a3[jj]+=w_ao_m2s[(o*3+jj)*8+(ih*4+ii)]*xh[ii][0];
  }
  for(int j2=ih*12;j2<ih*12+12;j2++){
    #pragma unroll
    for(int jj=0;jj<3;jj++) a3[jj]+=w_ao_s2s[(o*3+jj)*24+j2]*xs[j2];
  }
  #pragma unroll
  for(int p=0;p<16;p++) y[p]+=__shfl_xor(y[p],8);
  #pragma unroll
  for(int jj=0;jj<3;jj++) a3[jj]+=__shfl_xor(a3[jj],8);

  // residual + norms
  float hch[16]; float sqv=0.f;
  { const float4* hg=(const float4*)(h_mv+(size_t)tt*128+o*16);
    #pragma unroll
    for(int r4=0;r4<4;r4++){ float4 v=hg[r4];
      hch[r4*4]=v.x+y[r4*4]; hch[r4*4+1]=v.y+y[r4*4+1];
      hch[r4*4+2]=v.z+y[r4*4+2]; hch[r4*4+3]=v.w+y[r4*4+3]; } }
  #pragma unroll
  for(int p=0;p<16;p++) sqv+=FINNER[p]*hch[p]*hch[p];
  sqv+=__shfl_xor(sqv,1); sqv+=__shfl_xor(sqv,2); sqv+=__shfl_xor(sqv,4);
  float dmv=rsqrtf(sqv*0.125f+0.01f);
  float hs3[3]; float ssq=0.f;
  #pragma unroll
  for(int jj=0;jj<3;jj++){
    float v=h_s[(size_t)tt*24+o*3+jj]+a3[jj];
    hs3[jj]=v; ssq+=v*v;
  }
  ssq+=__shfl_xor(ssq,1); ssq+=__shfl_xor(ssq,2); ssq+=__shfl_xor(ssq,4);
  float dss=rsqrtf(ssq*(1.f/24.f)+0.01f);

  float* nsbuf=&NS[tl*152];
  if(ih==0){
    #pragma unroll
    for(int p=0;p<16;p++) nsbuf[o*16+p]=hch[p]*dmv;
    #pragma unroll
    for(int jj=0;jj<3;jj++) nsbuf[128+o*3+jj]=hs3[jj]*dss;
  }
  __syncthreads();

  // m1: lane = output channel ln=0..15
  float u[16];
  #pragma unroll
  for(int p=0;p<16;p++) u[p]=0.f;
  for(int i=0;i<8;i++){
    float xi[16];
    const float4* xs4=(const float4*)&nsbuf[i*16];
    #pragma unroll
    for(int r4=0;r4<4;r4++){ float4 v=xs4[r4]; xi[r4*4]=v.x; xi[r4*4+1]=v.y; xi[r4*4+2]=v.z; xi[r4*4+3]=v.w; }
    const float* wi=w_m1_mv+ln*72+i*9;
    #pragma unroll
    for(int p=0;p<16;p++){
      u[p]+=wi[GRADE[p]]*xi[p];
      if(AUGK[p]>=0) u[p]+=wi[AUGK[p]]*xi[AUGS[p]];
    }
  }
  float e1=b_m1_mv[ln];
  for(int j2=0;j2<24;j2++) e1+=w_m1_s2mv[ln*24+j2]*nsbuf[128+j2];
  u[0]+=e1;
  { float* uu=&U[tl*264];
    #pragma unroll
    for(int p=0;p<16;p++) uu[ln*16+p]=u[p]; }
  if(ih==0){
    float s3[3];
    #pragma unroll
    for(int jj=0;jj<3;jj++) s3[jj]=b_m1_s[o*3+jj];
    for(int j2=0;j2<24;j2++){
      float s=nsbuf[128+j2];
      #pragma unroll
      for(int jj=0;jj<3;jj++) s3[jj]+=w_m1_s2s[(o*3+jj)*24+j2]*s;
    }
    for(int i=0;i<8;i++){
      float x0=nsbuf[i*16];
      #pragma unroll
      for(int jj=0;jj<3;jj++) s3[jj]+=w_m1_m2s[(o*3+jj)*8+i]*x0;
    }
    #pragma unroll
    for(int jj=0;jj<3;jj++) GSm[tl*24+o*3+jj]=gelu_f(s3[jj]);
  }
  __syncthreads();

  // GP (o<4) / JOIN (o>=4): product o, component half ih
  { const int*   TI=(o<4)? GPI : JNI;
    const float* TS=(o<4)? GPS : JNS;
    const float* uu=&U[tl*264];
    const float* lft=&uu[((o<4)? o : (4+o))*16];
    const float* rgt=&uu[((o<4)? (4+o) : (8+o))*16];
    float* gg=&G[tl*136];
    #pragma unroll
    for(int kk=0;kk<8;kk++){
      int k=ih*8+kk;
      float accv=0.f;
      #pragma unroll
      for(int e2=0;e2<16;e2++){
        int ij=TI[k*16+e2]; float sg=TS[k*16+e2];
        accv += sg * lft[ij&15] * rgt[ij>>4];
      }
      gg[o*16+k]=accv;
    }
  }
  __syncthreads();
  if(ih==0){
    float* gg=&G[tl*136];
    float gt=gelu_f(gg[o*16]);
    #pragma unroll
    for(int p=0;p<16;p++) gg[o*16+p]*=gt;
  }
  __syncthreads();

  // m2: channel o, i-half + j-half, combine
  float y2[16];
  #pragma unroll
  for(int p=0;p<16;p++) y2[p]=0.f;
  #pragma unroll
  for(int ii=0;ii<4;ii++){
    float xi[16];
    const float4* gi=(const float4*)&G[tl*136+(ih*4+ii)*16];
    #pragma unroll
    for(int r4=0;r4<4;r4++){ float4 v=gi[r4]; xi[r4*4]=v.x; xi[r4*4+1]=v.y; xi[r4*4+2]=v.z; xi[r4*4+3]=v.w; }
    const float* wi=w_m2_mv+o*72+(ih*4+ii)*9;
    #pragma unroll
    for(int p=0;p<16;p++){
      y2[p]+=wi[GRADE[p]]*xi[p];
      if(AUGK[p]>=0) y2[p]+=wi[AUGK[p]]*xi[AUGS[p]];
    }
  }
  float e2=(ih==0)? b_m2_mv[o] : 0.f;
  for(int j2=ih*12;j2<ih*12+12;j2++) e2+=w_m2_s2mv[o*24+j2]*GSm[tl*24+j2];
  y2[0]+=e2;
  #pragma unroll
  for(int p=0;p<16;p++) y2[p]+=__shfl_xor(y2[p],8);

  float hf[16];
  #pragma unroll
  for(int p=0;p<16;p++) hf[p]=hch[p]+y2[p];

  const float* wout=w_out_mv+o*9;
  float c5 =wout[2]*hf[5] +wout[6]*hf[2];
  float c6 =wout[2]*hf[6] +wout[6]*hf[3];
  float c7 =wout[2]*hf[7] +wout[6]*hf[4];
  float c11=wout[3]*hf[11]+wout[7]*hf[8];
  float c12=wout[3]*hf[12]+wout[7]*hf[9];
  float c13=wout[3]*hf[13]+wout[7]*hf[10];
  float c14=wout[3]*hf[14];
  #pragma unroll
  for(int mk=1; mk<8; mk<<=1){
    c5+=__shfl_xor(c5,mk); c6+=__shfl_xor(c6,mk); c7+=__shfl_xor(c7,mk);
    c11+=__shfl_xor(c11,mk); c12+=__shfl_xor(c12,mk);
    c13+=__shfl_xor(c13,mk); c14+=__shfl_xor(c14,mk);
  }
  if(ln==0){
    float dd=c14;
    dd=(fabsf(dd)>0.001f)? dd : (dd>=0.f? 0.001f : -0.001f);
    float* op=out+(size_t)tt*6;
    op[0]=-c13/dd; op[1]=c12/dd; op[2]=-c11/dd;
    op[3]=2.f*c5; op[4]=2.f*c6; op[5]=2.f*c7;
  }
}

extern "C" void kernel_launch(void* const* d_in, const int* in_sizes, int n_in,
                              void* d_out, int out_size, void* d_ws, size_t ws_size,
                              hipStream_t stream)
{
  (void)in_sizes; (void)n_in; (void)out_size; (void)ws_size;
  const float* x         =(const float*)d_in[0];
  const float* w_in_mv   =(const float*)d_in[1];
  const float* b_in_mv   =(const float*)d_in[2];
  const float* w_in_m2s  =(const float*)d_in[3];
  const float* b_in_s    =(const float*)d_in[4];
  const float* w_qkv_mv  =(const float*)d_in[5];
  const float* w_qkv_s2mv=(const float*)d_in[6];
  const float* w_qkv_m2s =(const float*)d_in[7];
  const float* w_qkv_s2s =(const float*)d_in[8];
  const float* w_ao_mv   =(const float*)d_in[9];
  const float* w_ao_s2mv =(const float*)d_in[10];
  const float* w_ao_m2s  =(const float*)d_in[11];
  const float* w_ao_s2s  =(const float*)d_in[12];
  const float* b_ao_mv   =(const float*)d_in[13];
  const float* b_ao_s    =(const float*)d_in[14];
  const float* w_m1_mv   =(const float*)d_in[15];
  const float* w_m1_s2mv =(const float*)d_in[16];
  const float* w_m1_m2s  =(const float*)d_in[17];
  const float* w_m1_s2s  =(const float*)d_in[18];
  const float* b_m1_mv   =(const float*)d_in[19];
  const float* b_m1_s    =(const float*)d_in[20];
  const float* w_m2_mv   =(const float*)d_in[21];
  const float* w_m2_s2mv =(const float*)d_in[22];
  const float* b_m2_mv   =(const float*)d_in[25];
  const float* w_out_mv  =(const float*)d_in[27];
  float* outp=(float*)d_out;

  float* ws=(float*)d_ws;
  size_t off=0;
  float* h_mv = ws+off; off+=(size_t)BTOK*128;
  float* h_s  = ws+off; off+=(size_t)BTOK*24;
  float* qpk  = ws+off; off+=(size_t)16*T_*12;
  float* kpk  = ws+off; off+=(size_t)16*T_*12;
  float* vpk  = ws+off; off+=(size_t)16*T_*20;
  float* part = ws+off; off+=(size_t)16*NSLOT*128*20;

  k_in  <<<BTOK/4,64,0,stream>>>(x,w_in_mv,b_in_mv,w_in_m2s,b_in_s,
                                 w_qkv_mv,w_qkv_s2mv,w_qkv_m2s,w_qkv_s2s,
                                 h_mv,h_s,qpk,kpk,vpk);
  k_attn<<<16*NSLOT,256,0,stream>>>(qpk,kpk,vpk,part);
  k_tail<<<BTOK/4,64,0,stream>>>(part,
                                 w_ao_mv,w_ao_s2mv,w_ao_m2s,w_ao_s2s,b_ao_mv,b_ao_s,
                                 h_mv,h_s,
                                 w_m1_mv,w_m1_s2mv,w_m1_m2s,w_m1_s2s,b_m1_mv,b_m1_s,
                                 w_m2_mv,w_m2_s2mv,b_m2_mv,w_out_mv,outp);
}

// Round 7
// 108.949 us; speedup vs baseline: 1.3681x; 1.3681x over previous
//
#include <hip/hip_runtime.h>
#include <math.h>

#define T_    2048
#define BTOK  4096   // B * T
#define KB    64
#define NSLOT 72     // sum over 16 strips of ceil((s+1)/2)

namespace {
constexpr int GRADE[16] = {0,1,1,1,1,2,2,2,2,2,2,3,3,3,3,4};
constexpr int AUGK[16]  = {-1,5,-1,-1,-1,6,6,6,-1,-1,-1,7,7,7,-1,8};
constexpr int AUGS[16]  = { 0,0, 0, 0, 0,2,3,4, 0, 0, 0,8,9,10,0,14};
constexpr float FINNER[16] = {1.f,0.f,1.f,1.f,1.f,0.f,0.f,0.f,1.f,1.f,1.f,0.f,0.f,0.f,1.f,0.f};
}

__device__ __forceinline__ float gelu_f(float v){
  return 0.5f*v*(1.f + erff(v*0.70710678118654752f));
}

__device__ __forceinline__ int rsign_d(int a, int b){
  int s=0; a>>=1; while(a){ s += __popc(a&b); a>>=1; } return (s&1) ? -1 : 1;
}

// ---- K_A: embed + in-linear + norm + QKV projections + pack --------------
// 64 threads = 4 tokens x 16 lanes (8 channels x 2 input-halves).
__global__ void __launch_bounds__(64) k_in(
    const float* __restrict__ x,
    const float* __restrict__ w_in_mv, const float* __restrict__ b_in_mv,
    const float* __restrict__ w_in_m2s, const float* __restrict__ b_in_s,
    const float* __restrict__ w_mv, const float* __restrict__ w_s2mv,
    const float* __restrict__ w_m2s, const float* __restrict__ w_s2s,
    float* __restrict__ h_mv, float* __restrict__ h_s,
    float* __restrict__ qp_, float* __restrict__ kp_, float* __restrict__ vp_)
{
  __shared__ float NS[4*152];   // per token: n_mv 128 + n_s 24
  int tid=threadIdx.x, tl=tid>>4, ln=tid&15;
  int o=ln&7, ih=ln>>3;
  int tt=blockIdx.x*4+tl;
  int b=tt>>11, t=tt&(T_-1);
  const float* xp = x+(size_t)tt*6;
  float mv[16];
  #pragma unroll
  for(int p=0;p<16;p++) mv[p]=0.f;
  mv[0]=1.f; mv[14]=1.f;
  mv[13]=-xp[0]; mv[12]=xp[1]; mv[11]=-xp[2];
  mv[5]=0.5f*xp[3]; mv[6]=0.5f*xp[4]; mv[7]=0.5f*xp[5];

  const float* wo=w_in_mv+o*9;
  float h[16]; float sq=0.f;
  #pragma unroll
  for(int p=0;p<16;p++){
    float v=wo[GRADE[p]]*mv[p];
    if(AUGK[p]>=0) v+=wo[AUGK[p]]*mv[AUGS[p]];
    if(p==0) v+=b_in_mv[o];
    h[p]=v; sq+=FINNER[p]*v*v;
  }
  sq+=__shfl_xor(sq,1); sq+=__shfl_xor(sq,2); sq+=__shfl_xor(sq,4);
  float dmv=rsqrtf(sq*0.125f+0.01f);
  float hs[3]; float ssq=0.f;
  #pragma unroll
  for(int jj=0;jj<3;jj++){ float v=w_in_m2s[o*3+jj]+b_in_s[o*3+jj]; hs[jj]=v; ssq+=v*v; }
  ssq+=__shfl_xor(ssq,1); ssq+=__shfl_xor(ssq,2); ssq+=__shfl_xor(ssq,4);
  float dss=rsqrtf(ssq*(1.f/24.f)+0.01f);

  float* ns=&NS[tl*152];
  if(ih==0){
    float4* hg=(float4*)(h_mv+(size_t)tt*128+o*16);
    hg[0]=make_float4(h[0],h[1],h[2],h[3]);
    hg[1]=make_float4(h[4],h[5],h[6],h[7]);
    hg[2]=make_float4(h[8],h[9],h[10],h[11]);
    hg[3]=make_float4(h[12],h[13],h[14],h[15]);
    #pragma unroll
    for(int jj=0;jj<3;jj++) h_s[(size_t)tt*24+o*3+jj]=hs[jj];
    #pragma unroll
    for(int p=0;p<16;p++) ns[o*16+p]=h[p]*dmv;
    #pragma unroll
    for(int jj=0;jj<3;jj++) ns[128+o*3+jj]=hs[jj]*dss;
  }
  __syncthreads();

  float yq[16],yk[16],yv[16];
  #pragma unroll
  for(int p=0;p<16;p++){ yq[p]=0.f; yk[p]=0.f; yv[p]=0.f; }
  float nx0p[4];
  const float* wq=w_mv+o*72;
  #pragma unroll
  for(int ii=0;ii<4;ii++){
    int i=ih*4+ii;
    float xi[16];
    const float4* xs4=(const float4*)&ns[i*16];
    #pragma unroll
    for(int r4=0;r4<4;r4++){ float4 v=xs4[r4]; xi[r4*4]=v.x; xi[r4*4+1]=v.y; xi[r4*4+2]=v.z; xi[r4*4+3]=v.w; }
    nx0p[ii]=xi[0];
    const float* aq=wq+i*9; const float* ak=aq+576; const float* av=aq+1152;
    #pragma unroll
    for(int p=0;p<16;p++){
      float bb=xi[p];
      yq[p]+=aq[GRADE[p]]*bb; yk[p]+=ak[GRADE[p]]*bb; yv[p]+=av[GRADE[p]]*bb;
      if(AUGK[p]>=0){
        float au=xi[AUGS[p]];
        yq[p]+=aq[AUGK[p]]*au; yk[p]+=ak[AUGK[p]]*au; yv[p]+=av[AUGK[p]]*au;
      }
    }
  }
  float eq=0.f,ek=0.f,ev=0.f;
  float sq3[3]={0,0,0}, sk3[3]={0,0,0}, sv3[3]={0,0,0};
  for(int j=ih*12;j<ih*12+12;j++){
    float s=ns[128+j];
    eq+=w_s2mv[o*24+j]*s; ek+=w_s2mv[192+o*24+j]*s; ev+=w_s2mv[384+o*24+j]*s;
    #pragma unroll
    for(int jj=0;jj<3;jj++){
      int d=o*3+jj;
      sq3[jj]+=w_s2s[d*24+j]*s;
      sk3[jj]+=w_s2s[576+d*24+j]*s;
      sv3[jj]+=w_s2s[1152+d*24+j]*s;
    }
  }
  #pragma unroll
  for(int ii=0;ii<4;ii++){
    int i=ih*4+ii;
    #pragma unroll
    for(int jj=0;jj<3;jj++){
      int d=o*3+jj;
      sq3[jj]+=w_m2s[d*8+i]*nx0p[ii];
      sk3[jj]+=w_m2s[192+d*8+i]*nx0p[ii];
      sv3[jj]+=w_m2s[384+d*8+i]*nx0p[ii];
    }
  }
  yq[0]+=eq; yk[0]+=ek; yv[0]+=ev;
  #pragma unroll
  for(int p=0;p<16;p++){
    yq[p]+=__shfl_xor(yq[p],8);
    yk[p]+=__shfl_xor(yk[p],8);
    yv[p]+=__shfl_xor(yv[p],8);
  }
  #pragma unroll
  for(int jj=0;jj<3;jj++){
    sq3[jj]+=__shfl_xor(sq3[jj],8);
    sk3[jj]+=__shfl_xor(sk3[jj],8);
    sv3[jj]+=__shfl_xor(sv3[jj],8);
  }

  const float scale = 0.3015113445777636f;  // 1/sqrt(11)
  size_t rb=((size_t)(b*8+o)*T_+t);
  if(ih==0){
    float4* qr=(float4*)(qp_+rb*12);
    qr[0]=make_float4(yq[0]*scale, yq[2]*scale, yq[3]*scale, yq[4]*scale);
    qr[1]=make_float4(yq[8]*scale, yq[9]*scale, yq[10]*scale, yq[14]*scale);
    qr[2]=make_float4(sq3[0]*scale, sq3[1]*scale, sq3[2]*scale, 0.f);
    float4* vr=(float4*)(vp_+rb*20);
    vr[0]=make_float4(yv[0],yv[1],yv[2],yv[3]);
    vr[1]=make_float4(yv[4],yv[5],yv[6],yv[7]);
    vr[2]=make_float4(yv[8],yv[9],yv[10],yv[11]);
  } else {
    float4* kr=(float4*)(kp_+rb*12);
    kr[0]=make_float4(yk[0],yk[2],yk[3],yk[4]);
    kr[1]=make_float4(yk[8],yk[9],yk[10],yk[14]);
    kr[2]=make_float4(sk3[0],sk3[1],sk3[2],0.f);
    float4* vr=(float4*)(vp_+rb*20);
    vr[3]=make_float4(yv[12],yv[13],yv[14],yv[15]);
    vr[4]=make_float4(sv3[0],sv3[1],sv3[2],0.f);
  }
}

// ---- K_B: attention, no-max softmax, balanced flash-split ----------------
// 256 thr = 32 q-threads x 8 key-lanes; 4 queries/thread (128-query strip).
// 1152 blocks = 16 bh x 72 slots; each slot <= 4 key-tiles. Heavy-first.
// launch_bounds(256,1): do NOT cap VGPRs — live state ~190 regs; forcing
// 3 waves/EU spilled ~100 regs to scratch (R5/R6: FETCH +8MB, VALU 26%).
__global__ void __launch_bounds__(256,1) k_attn(
    const float* __restrict__ qp_, const float* __restrict__ kp_,
    const float* __restrict__ vp_,
    float* __restrict__ part)
{
  __shared__ float Kt[KB*12];
  __shared__ float Vt[KB*20];
  int tid=threadIdx.x; int qi=tid>>3, ki=tid&7;
  int j=blockIdx.x;
  int bh=j&15;
  int z=NSLOT-1-(j>>4);          // ascending slot id; j ordered heavy-first
  // decode z -> (strip s, split sp): c(s)=(s+2)>>1
  int s=0, bse=0;
  while (bse + ((s+2)>>1) <= z){ bse += (s+2)>>1; s++; }
  int sp = z - bse;
  int c  = (s+2)>>1;
  int ntiles = 2*(s+1);
  int t0 = sp*ntiles/c, t1 = (sp+1)*ntiles/c;
  int q0 = s*128;

  float qp[4][12];
  int kend[4];
  #pragma unroll
  for(int w=0;w<4;w++){
    int q=q0+qi+32*w;
    kend[w]=(q&~15)+16;
    const float4* p4=(const float4*)(qp_+((size_t)bh*T_+q)*12);
    #pragma unroll
    for(int i=0;i<3;i++){ float4 v=p4[i];
      qp[w][i*4]=v.x; qp[w][i*4+1]=v.y; qp[w][i*4+2]=v.z; qp[w][i*4+3]=v.w; }
  }

  float acc[4][20];
  #pragma unroll
  for(int w=0;w<4;w++)
    #pragma unroll
    for(int p=0;p<20;p++) acc[w][p]=0.f;

  const float4* gk=(const float4*)(kp_+(size_t)bh*T_*12);
  const float4* gv=(const float4*)(vp_+(size_t)bh*T_*20);

  for(int tile=t0; tile<t1; ++tile){
    int s0=tile*KB;
    int i1=tid, i2=tid+256;
    if(i1<192) ((float4*)Kt)[i1]=gk[s0*3+i1];
    else       ((float4*)Vt)[i1-192]=gv[s0*5+(i1-192)];
    ((float4*)Vt)[i2-192]=gv[s0*5+(i2-192)];
    __syncthreads();
    #pragma unroll 2
    for(int it=0; it<8; ++it){
      int r=ki+it*8;
      int skey=s0+r;
      const float4* K4=(const float4*)&Kt[r*12];
      float4 k0=K4[0],k1=K4[1],k2=K4[2];
      float cc[4];
      #pragma unroll
      for(int w=0;w<4;w++){
        float d = qp[w][0]*k0.x+qp[w][1]*k0.y+qp[w][2]*k0.z+qp[w][3]*k0.w
                + qp[w][4]*k1.x+qp[w][5]*k1.y+qp[w][6]*k1.z+qp[w][7]*k1.w
                + qp[w][8]*k2.x+qp[w][9]*k2.y+qp[w][10]*k2.z;
        cc[w]=(skey<kend[w])? __expf(d) : 0.f;
      }
      const float4* V4=(const float4*)&Vt[r*20];
      float4 v0=V4[0],v1=V4[1],v2=V4[2],v3=V4[3],v4=V4[4];
      #pragma unroll
      for(int w=0;w<4;w++){
        float cw=cc[w];
        acc[w][0]+=cw*v0.x; acc[w][1]+=cw*v0.y; acc[w][2]+=cw*v0.z; acc[w][3]+=cw*v0.w;
        acc[w][4]+=cw*v1.x; acc[w][5]+=cw*v1.y; acc[w][6]+=cw*v1.z; acc[w][7]+=cw*v1.w;
        acc[w][8]+=cw*v2.x; acc[w][9]+=cw*v2.y; acc[w][10]+=cw*v2.z; acc[w][11]+=cw*v2.w;
        acc[w][12]+=cw*v3.x; acc[w][13]+=cw*v3.y; acc[w][14]+=cw*v3.z; acc[w][15]+=cw*v3.w;
        acc[w][16]+=cw;
        acc[w][17]+=cw*v4.x; acc[w][18]+=cw*v4.y; acc[w][19]+=cw*v4.z;
      }
    }
    __syncthreads();
  }

  // butterfly sum across 8 key-lanes (pure adds)
  #pragma unroll
  for(int mk=1; mk<8; mk<<=1){
    #pragma unroll
    for(int w=0;w<4;w++)
      #pragma unroll
      for(int p=0;p<20;p++) acc[w][p]+=__shfl_xor(acc[w][p],mk);
  }

  if(ki==0){
    #pragma unroll
    for(int w=0;w<4;w++){
      float* pr = part + ((size_t)(bh*NSLOT + z)*128 + qi + 32*w)*20;
      float4* p4=(float4*)pr;
      p4[0]=make_float4(acc[w][0],acc[w][1],acc[w][2],acc[w][3]);
      p4[1]=make_float4(acc[w][4],acc[w][5],acc[w][6],acc[w][7]);
      p4[2]=make_float4(acc[w][8],acc[w][9],acc[w][10],acc[w][11]);
      p4[3]=make_float4(acc[w][12],acc[w][13],acc[w][14],acc[w][15]);
      p4[4]=make_float4(acc[w][16],acc[w][17],acc[w][18],acc[w][19]);
    }
  }
}

// ---- K_C: combine partials + ao + norm + m1 + GP/join + m2 + out ---------
__global__ void __launch_bounds__(64) k_tail(
    const float* __restrict__ part,
    const float* __restrict__ w_ao_mv, const float* __restrict__ w_ao_s2mv,
    const float* __restrict__ w_ao_m2s, const float* __restrict__ w_ao_s2s,
    const float* __restrict__ b_ao_mv, const float* __restrict__ b_ao_s,
    const float* __restrict__ h_mv, const float* __restrict__ h_s,
    const float* __restrict__ w_m1_mv, const float* __restrict__ w_m1_s2mv,
    const float* __restrict__ w_m1_m2s, const float* __restrict__ w_m1_s2s,
    const float* __restrict__ b_m1_mv, const float* __restrict__ b_m1_s,
    const float* __restrict__ w_m2_mv, const float* __restrict__ w_m2_s2mv,
    const float* __restrict__ b_m2_mv,
    const float* __restrict__ w_out_mv,
    float* __restrict__ out)
{
  __shared__ int   GPI[256]; __shared__ float GPS[256];
  __shared__ int   JNI[256]; __shared__ float JNS[256];
  __shared__ float OS[4*152];
  __shared__ float NS[4*152];
  __shared__ float U[4*264];
  __shared__ float G[4*136];
  __shared__ float GSm[4*24];
  int tid=threadIdx.x, tl=tid>>4, ln=tid&15;
  int o=ln&7, ih=ln>>3;
  int tt=blockIdx.x*4+tl;

  { // build tables (threads 0..31)
    const int mask_of[16]={0,1,2,4,8,3,5,9,6,10,12,7,11,13,14,15};
    const int idx_of[16] ={0,1,2,5,3,6,8,11,4,7,9,12,10,13,14,15};
    if (tid<16){
      int k=tid, km=mask_of[k], slotn=0;
      for(int i=0;i<16;i++){
        int im=mask_of[i], jm=im^km;
        if(im & jm & 1) continue;
        GPI[k*16+slotn]=i|(idx_of[jm]<<4);
        GPS[k*16+slotn]=(float)rsign_d(im,jm);
        slotn++;
      }
      for(;slotn<16;slotn++){ GPI[k*16+slotn]=0; GPS[k*16+slotn]=0.f; }
    } else if (tid<32){
      int p=tid-16, pm=mask_of[p], rest=15&~pm, slotn=0;
      for(int u=0;u<16;u++){
        if(u & ~rest) continue;
        int am=pm|u, bm=pm|(rest&~u);
        float s=(float)( rsign_d(pm,15&~pm)*rsign_d(15&~am,15&~bm)
                        *rsign_d(am,15&~am)*rsign_d(bm,15&~bm) );
        JNI[p*16+slotn]=idx_of[am]|(idx_of[bm]<<4);
        JNS[p*16+slotn]=s;
        slotn++;
      }
      for(;slotn<16;slotn++){ JNI[p*16+slotn]=0; JNS[p*16+slotn]=0.f; }
    }
  }

  // combine attention partials: lane = (head h, comp-half)
  {
    int b=tt>>11, t=tt&(T_-1);
    int strip=t>>7, qi=t&127;
    int h=ln>>1, half=ln&1;
    int nsp=(strip+2)>>1;
    int kk=strip>>1;
    int rbase=(strip&1)? (kk+1)*(kk+1) : kk*kk+kk;
    const float* pb = part + ((size_t)((b*8+h)*NSLOT+rbase)*128 + qi)*20;
    float am[8]={0,0,0,0,0,0,0,0};
    float lv=0.f, s0=0.f, s1=0.f, s2=0.f;
    for(int spp=0; spp<nsp; ++spp){
      const float4* p4=(const float4*)(pb + (size_t)spp*128*20);
      float4 a=p4[half*2], b4=p4[half*2+1], meta=p4[4];
      am[0]+=a.x; am[1]+=a.y; am[2]+=a.z; am[3]+=a.w;
      am[4]+=b4.x; am[5]+=b4.y; am[6]+=b4.z; am[7]+=b4.w;
      lv+=meta.x; s0+=meta.y; s1+=meta.z; s2+=meta.w;
    }
    float inv=1.f/lv;
    float* os=&OS[tl*152];
    #pragma unroll
    for(int p=0;p<8;p++) os[h*16+half*8+p]=am[p]*inv;
    if(half==1){ os[128+h*3]=s0*inv; os[128+h*3+1]=s1*inv; os[128+h*3+2]=s2*inv; }
  }
  __syncthreads();

  const float* os=&OS[tl*152];
  float xh[4][16];
  #pragma unroll
  for(int ii=0;ii<4;ii++){
    #pragma unroll
    for(int p=0;p<16;p++) xh[ii][p]=os[(ih*4+ii)*16+p];
  }
  float xs[24];
  #pragma unroll
  for(int jj=0;jj<24;jj++) xs[jj]=os[128+jj];

  // ao: channel o, partial over i-half and j-half
  float y[16];
  #pragma unroll
  for(int p=0;p<16;p++) y[p]=0.f;
  #pragma unroll
  for(int ii=0;ii<4;ii++){
    const float* wi=w_ao_mv+o*72+(ih*4+ii)*9;
    #pragma unroll
    for(int p=0;p<16;p++){
      y[p]+=wi[GRADE[p]]*xh[ii][p];
      if(AUGK[p]>=0) y[p]+=wi[AUGK[p]]*xh[ii][AUGS[p]];
    }
  }
  float e=(ih==0)? b_ao_mv[o] : 0.f;
  for(int j2=ih*12;j2<ih*12+12;j2++) e+=w_ao_s2mv[o*24+j2]*xs[j2];
  y[0]+=e;
  float a3[3];
  #pragma unroll
  for(int jj=0;jj<3;jj++) a3[jj]=(ih==0)? b_ao_s[o*3+jj] : 0.f;
  #pragma unroll
  for(int ii=0;ii<4;ii++){
    #pragma unroll
    for(int jj=0;jj<3;jj++) a3[jj]+=w_ao_m2s[(o*3+jj)*8+(ih*4+ii)]*xh[ii][0];
  }
  for(int j2=ih*12;j2<ih*12+12;j2++){
    #pragma unroll
    for(int jj=0;jj<3;jj++) a3[jj]+=w_ao_s2s[(o*3+jj)*24+j2]*xs[j2];
  }
  #pragma unroll
  for(int p=0;p<16;p++) y[p]+=__shfl_xor(y[p],8);
  #pragma unroll
  for(int jj=0;jj<3;jj++) a3[jj]+=__shfl_xor(a3[jj],8);

  // residual + norms
  float hch[16]; float sqv=0.f;
  { const float4* hg=(const float4*)(h_mv+(size_t)tt*128+o*16);
    #pragma unroll
    for(int r4=0;r4<4;r4++){ float4 v=hg[r4];
      hch[r4*4]=v.x+y[r4*4]; hch[r4*4+1]=v.y+y[r4*4+1];
      hch[r4*4+2]=v.z+y[r4*4+2]; hch[r4*4+3]=v.w+y[r4*4+3]; } }
  #pragma unroll
  for(int p=0;p<16;p++) sqv+=FINNER[p]*hch[p]*hch[p];
  sqv+=__shfl_xor(sqv,1); sqv+=__shfl_xor(sqv,2); sqv+=__shfl_xor(sqv,4);
  float dmv=rsqrtf(sqv*0.125f+0.01f);
  float hs3[3]; float ssq=0.f;
  #pragma unroll
  for(int jj=0;jj<3;jj++){
    float v=h_s[(size_t)tt*24+o*3+jj]+a3[jj];
    hs3[jj]=v; ssq+=v*v;
  }
  ssq+=__shfl_xor(ssq,1); ssq+=__shfl_xor(ssq,2); ssq+=__shfl_xor(ssq,4);
  float dss=rsqrtf(ssq*(1.f/24.f)+0.01f);

  float* nsbuf=&NS[tl*152];
  if(ih==0){
    #pragma unroll
    for(int p=0;p<16;p++) nsbuf[o*16+p]=hch[p]*dmv;
    #pragma unroll
    for(int jj=0;jj<3;jj++) nsbuf[128+o*3+jj]=hs3[jj]*dss;
  }
  __syncthreads();

  // m1: lane = output channel ln=0..15
  float u[16];
  #pragma unroll
  for(int p=0;p<16;p++) u[p]=0.f;
  for(int i=0;i<8;i++){
    float xi[16];
    const float4* xs4=(const float4*)&nsbuf[i*16];
    #pragma unroll
    for(int r4=0;r4<4;r4++){ float4 v=xs4[r4]; xi[r4*4]=v.x; xi[r4*4+1]=v.y; xi[r4*4+2]=v.z; xi[r4*4+3]=v.w; }
    const float* wi=w_m1_mv+ln*72+i*9;
    #pragma unroll
    for(int p=0;p<16;p++){
      u[p]+=wi[GRADE[p]]*xi[p];
      if(AUGK[p]>=0) u[p]+=wi[AUGK[p]]*xi[AUGS[p]];
    }
  }
  float e1=b_m1_mv[ln];
  for(int j2=0;j2<24;j2++) e1+=w_m1_s2mv[ln*24+j2]*nsbuf[128+j2];
  u[0]+=e1;
  { float* uu=&U[tl*264];
    #pragma unroll
    for(int p=0;p<16;p++) uu[ln*16+p]=u[p]; }
  if(ih==0){
    float s3[3];
    #pragma unroll
    for(int jj=0;jj<3;jj++) s3[jj]=b_m1_s[o*3+jj];
    for(int j2=0;j2<24;j2++){
      float s=nsbuf[128+j2];
      #pragma unroll
      for(int jj=0;jj<3;jj++) s3[jj]+=w_m1_s2s[(o*3+jj)*24+j2]*s;
    }
    for(int i=0;i<8;i++){
      float x0=nsbuf[i*16];
      #pragma unroll
      for(int jj=0;jj<3;jj++) s3[jj]+=w_m1_m2s[(o*3+jj)*8+i]*x0;
    }
    #pragma unroll
    for(int jj=0;jj<3;jj++) GSm[tl*24+o*3+jj]=gelu_f(s3[jj]);
  }
  __syncthreads();

  // GP (o<4) / JOIN (o>=4): product o, component half ih
  { const int*   TI=(o<4)? GPI : JNI;
    const float* TS=(o<4)? GPS : JNS;
    const float* uu=&U[tl*264];
    const float* lft=&uu[((o<4)? o : (4+o))*16];
    const float* rgt=&uu[((o<4)? (4+o) : (8+o))*16];
    float* gg=&G[tl*136];
    #pragma unroll
    for(int kk=0;kk<8;kk++){
      int k=ih*8+kk;
      float accv=0.f;
      #pragma unroll
      for(int e2=0;e2<16;e2++){
        int ij=TI[k*16+e2]; float sg=TS[k*16+e2];
        accv += sg * lft[ij&15] * rgt[ij>>4];
      }
      gg[o*16+k]=accv;
    }
  }
  __syncthreads();
  if(ih==0){
    float* gg=&G[tl*136];
    float gt=gelu_f(gg[o*16]);
    #pragma unroll
    for(int p=0;p<16;p++) gg[o*16+p]*=gt;
  }
  __syncthreads();

  // m2: channel o, i-half + j-half, combine
  float y2[16];
  #pragma unroll
  for(int p=0;p<16;p++) y2[p]=0.f;
  #pragma unroll
  for(int ii=0;ii<4;ii++){
    float xi[16];
    const float4* gi=(const float4*)&G[tl*136+(ih*4+ii)*16];
    #pragma unroll
    for(int r4=0;r4<4;r4++){ float4 v=gi[r4]; xi[r4*4]=v.x; xi[r4*4+1]=v.y; xi[r4*4+2]=v.z; xi[r4*4+3]=v.w; }
    const float* wi=w_m2_mv+o*72+(ih*4+ii)*9;
    #pragma unroll
    for(int p=0;p<16;p++){
      y2[p]+=wi[GRADE[p]]*xi[p];
      if(AUGK[p]>=0) y2[p]+=wi[AUGK[p]]*xi[AUGS[p]];
    }
  }
  float e2=(ih==0)? b_m2_mv[o] : 0.f;
  for(int j2=ih*12;j2<ih*12+12;j2++) e2+=w_m2_s2mv[o*24+j2]*GSm[tl*24+j2];
  y2[0]+=e2;
  #pragma unroll
  for(int p=0;p<16;p++) y2[p]+=__shfl_xor(y2[p],8);

  float hf[16];
  #pragma unroll
  for(int p=0;p<16;p++) hf[p]=hch[p]+y2[p];

  const float* wout=w_out_mv+o*9;
  float c5 =wout[2]*hf[5] +wout[6]*hf[2];
  float c6 =wout[2]*hf[6] +wout[6]*hf[3];
  float c7 =wout[2]*hf[7] +wout[6]*hf[4];
  float c11=wout[3]*hf[11]+wout[7]*hf[8];
  float c12=wout[3]*hf[12]+wout[7]*hf[9];
  float c13=wout[3]*hf[13]+wout[7]*hf[10];
  float c14=wout[3]*hf[14];
  #pragma unroll
  for(int mk=1; mk<8; mk<<=1){
    c5+=__shfl_xor(c5,mk); c6+=__shfl_xor(c6,mk); c7+=__shfl_xor(c7,mk);
    c11+=__shfl_xor(c11,mk); c12+=__shfl_xor(c12,mk);
    c13+=__shfl_xor(c13,mk); c14+=__shfl_xor(c14,mk);
  }
  if(ln==0){
    float dd=c14;
    dd=(fabsf(dd)>0.001f)? dd : (dd>=0.f? 0.001f : -0.001f);
    float* op=out+(size_t)tt*6;
    op[0]=-c13/dd; op[1]=c12/dd; op[2]=-c11/dd;
    op[3]=2.f*c5; op[4]=2.f*c6; op[5]=2.f*c7;
  }
}

extern "C" void kernel_launch(void* const* d_in, const int* in_sizes, int n_in,
                              void* d_out, int out_size, void* d_ws, size_t ws_size,
                              hipStream_t stream)
{
  (void)in_sizes; (void)n_in; (void)out_size; (void)ws_size;
  const float* x         =(const float*)d_in[0];
  const float* w_in_mv   =(const float*)d_in[1];
  const float* b_in_mv   =(const float*)d_in[2];
  const float* w_in_m2s  =(const float*)d_in[3];
  const float* b_in_s    =(const float*)d_in[4];
  const float* w_qkv_mv  =(const float*)d_in[5];
  const float* w_qkv_s2mv=(const float*)d_in[6];
  const float* w_qkv_m2s =(const float*)d_in[7];
  const float* w_qkv_s2s =(const float*)d_in[8];
  const float* w_ao_mv   =(const float*)d_in[9];
  const float* w_ao_s2mv =(const float*)d_in[10];
  const float* w_ao_m2s  =(const float*)d_in[11];
  const float* w_ao_s2s  =(const float*)d_in[12];
  const float* b_ao_mv   =(const float*)d_in[13];
  const float* b_ao_s    =(const float*)d_in[14];
  const float* w_m1_mv   =(const float*)d_in[15];
  const float* w_m1_s2mv =(const float*)d_in[16];
  const float* w_m1_m2s  =(const float*)d_in[17];
  const float* w_m1_s2s  =(const float*)d_in[18];
  const float* b_m1_mv   =(const float*)d_in[19];
  const float* b_m1_s    =(const float*)d_in[20];
  const float* w_m2_mv   =(const float*)d_in[21];
  const float* w_m2_s2mv =(const float*)d_in[22];
  const float* b_m2_mv   =(const float*)d_in[25];
  const float* w_out_mv  =(const float*)d_in[27];
  float* outp=(float*)d_out;

  float* ws=(float*)d_ws;
  size_t off=0;
  float* h_mv = ws+off; off+=(size_t)BTOK*128;
  float* h_s  = ws+off; off+=(size_t)BTOK*24;
  float* qpk  = ws+off; off+=(size_t)16*T_*12;
  float* kpk  = ws+off; off+=(size_t)16*T_*12;
  float* vpk  = ws+off; off+=(size_t)16*T_*20;
  float* part = ws+off; off+=(size_t)16*NSLOT*128*20;

  k_in  <<<BTOK/4,64,0,stream>>>(x,w_in_mv,b_in_mv,w_in_m2s,b_in_s,
                                 w_qkv_mv,w_qkv_s2mv,w_qkv_m2s,w_qkv_s2s,
                                 h_mv,h_s,qpk,kpk,vpk);
  k_attn<<<16*NSLOT,256,0,stream>>>(qpk,kpk,vpk,part);
  k_tail<<<BTOK/4,64,0,stream>>>(part,
                                 w_ao_mv,w_ao_s2mv,w_ao_m2s,w_ao_s2s,b_ao_mv,b_ao_s,
                                 h_mv,h_s,
                                 w_m1_mv,w_m1_s2mv,w_m1_m2s,w_m1_s2s,b_m1_mv,b_m1_s,
                                 w_m2_mv,w_m2_s2mv,b_m2_mv,w_out_mv,outp);
}

// Round 8
// 108.442 us; speedup vs baseline: 1.3745x; 1.0047x over previous
//
#include <hip/hip_runtime.h>
#include <math.h>

#define T_    2048
#define BTOK  4096   // B * T
#define KB    64
#define NSLOT 72     // sum over 16 strips of ceil((s+1)/2)

namespace {
constexpr int GRADE[16] = {0,1,1,1,1,2,2,2,2,2,2,3,3,3,3,4};
constexpr int AUGK[16]  = {-1,5,-1,-1,-1,6,6,6,-1,-1,-1,7,7,7,-1,8};
constexpr int AUGS[16]  = { 0,0, 0, 0, 0,2,3,4, 0, 0, 0,8,9,10,0,14};
constexpr float FINNER[16] = {1.f,0.f,1.f,1.f,1.f,0.f,0.f,0.f,1.f,1.f,1.f,0.f,0.f,0.f,1.f,0.f};
}

__device__ __forceinline__ float gelu_f(float v){
  return 0.5f*v*(1.f + erff(v*0.70710678118654752f));
}

__device__ __forceinline__ int rsign_d(int a, int b){
  int s=0; a>>=1; while(a){ s += __popc(a&b); a>>=1; } return (s&1) ? -1 : 1;
}

// ---- K_A: embed + in-linear + norm + QKV projections + pack --------------
// 64 threads = 4 tokens x 16 lanes (8 channels x 2 input-halves).
__global__ void __launch_bounds__(64) k_in(
    const float* __restrict__ x,
    const float* __restrict__ w_in_mv, const float* __restrict__ b_in_mv,
    const float* __restrict__ w_in_m2s, const float* __restrict__ b_in_s,
    const float* __restrict__ w_mv, const float* __restrict__ w_s2mv,
    const float* __restrict__ w_m2s, const float* __restrict__ w_s2s,
    float* __restrict__ h_mv, float* __restrict__ h_s,
    float* __restrict__ qp_, float* __restrict__ kp_, float* __restrict__ vp_)
{
  __shared__ float NS[4*152];   // per token: n_mv 128 + n_s 24
  int tid=threadIdx.x, tl=tid>>4, ln=tid&15;
  int o=ln&7, ih=ln>>3;
  int tt=blockIdx.x*4+tl;
  int b=tt>>11, t=tt&(T_-1);
  const float* xp = x+(size_t)tt*6;
  float mv[16];
  #pragma unroll
  for(int p=0;p<16;p++) mv[p]=0.f;
  mv[0]=1.f; mv[14]=1.f;
  mv[13]=-xp[0]; mv[12]=xp[1]; mv[11]=-xp[2];
  mv[5]=0.5f*xp[3]; mv[6]=0.5f*xp[4]; mv[7]=0.5f*xp[5];

  const float* wo=w_in_mv+o*9;
  float h[16]; float sq=0.f;
  #pragma unroll
  for(int p=0;p<16;p++){
    float v=wo[GRADE[p]]*mv[p];
    if(AUGK[p]>=0) v+=wo[AUGK[p]]*mv[AUGS[p]];
    if(p==0) v+=b_in_mv[o];
    h[p]=v; sq+=FINNER[p]*v*v;
  }
  sq+=__shfl_xor(sq,1); sq+=__shfl_xor(sq,2); sq+=__shfl_xor(sq,4);
  float dmv=rsqrtf(sq*0.125f+0.01f);
  float hs[3]; float ssq=0.f;
  #pragma unroll
  for(int jj=0;jj<3;jj++){ float v=w_in_m2s[o*3+jj]+b_in_s[o*3+jj]; hs[jj]=v; ssq+=v*v; }
  ssq+=__shfl_xor(ssq,1); ssq+=__shfl_xor(ssq,2); ssq+=__shfl_xor(ssq,4);
  float dss=rsqrtf(ssq*(1.f/24.f)+0.01f);

  float* ns=&NS[tl*152];
  if(ih==0){
    float4* hg=(float4*)(h_mv+(size_t)tt*128+o*16);
    hg[0]=make_float4(h[0],h[1],h[2],h[3]);
    hg[1]=make_float4(h[4],h[5],h[6],h[7]);
    hg[2]=make_float4(h[8],h[9],h[10],h[11]);
    hg[3]=make_float4(h[12],h[13],h[14],h[15]);
    #pragma unroll
    for(int jj=0;jj<3;jj++) h_s[(size_t)tt*24+o*3+jj]=hs[jj];
    #pragma unroll
    for(int p=0;p<16;p++) ns[o*16+p]=h[p]*dmv;
    #pragma unroll
    for(int jj=0;jj<3;jj++) ns[128+o*3+jj]=hs[jj]*dss;
  }
  __syncthreads();

  float yq[16],yk[16],yv[16];
  #pragma unroll
  for(int p=0;p<16;p++){ yq[p]=0.f; yk[p]=0.f; yv[p]=0.f; }
  float nx0p[4];
  const float* wq=w_mv+o*72;
  #pragma unroll
  for(int ii=0;ii<4;ii++){
    int i=ih*4+ii;
    float xi[16];
    const float4* xs4=(const float4*)&ns[i*16];
    #pragma unroll
    for(int r4=0;r4<4;r4++){ float4 v=xs4[r4]; xi[r4*4]=v.x; xi[r4*4+1]=v.y; xi[r4*4+2]=v.z; xi[r4*4+3]=v.w; }
    nx0p[ii]=xi[0];
    const float* aq=wq+i*9; const float* ak=aq+576; const float* av=aq+1152;
    #pragma unroll
    for(int p=0;p<16;p++){
      float bb=xi[p];
      yq[p]+=aq[GRADE[p]]*bb; yk[p]+=ak[GRADE[p]]*bb; yv[p]+=av[GRADE[p]]*bb;
      if(AUGK[p]>=0){
        float au=xi[AUGS[p]];
        yq[p]+=aq[AUGK[p]]*au; yk[p]+=ak[AUGK[p]]*au; yv[p]+=av[AUGK[p]]*au;
      }
    }
  }
  float eq=0.f,ek=0.f,ev=0.f;
  float sq3[3]={0,0,0}, sk3[3]={0,0,0}, sv3[3]={0,0,0};
  for(int j=ih*12;j<ih*12+12;j++){
    float s=ns[128+j];
    eq+=w_s2mv[o*24+j]*s; ek+=w_s2mv[192+o*24+j]*s; ev+=w_s2mv[384+o*24+j]*s;
    #pragma unroll
    for(int jj=0;jj<3;jj++){
      int d=o*3+jj;
      sq3[jj]+=w_s2s[d*24+j]*s;
      sk3[jj]+=w_s2s[576+d*24+j]*s;
      sv3[jj]+=w_s2s[1152+d*24+j]*s;
    }
  }
  #pragma unroll
  for(int ii=0;ii<4;ii++){
    int i=ih*4+ii;
    #pragma unroll
    for(int jj=0;jj<3;jj++){
      int d=o*3+jj;
      sq3[jj]+=w_m2s[d*8+i]*nx0p[ii];
      sk3[jj]+=w_m2s[192+d*8+i]*nx0p[ii];
      sv3[jj]+=w_m2s[384+d*8+i]*nx0p[ii];
    }
  }
  yq[0]+=eq; yk[0]+=ek; yv[0]+=ev;
  #pragma unroll
  for(int p=0;p<16;p++){
    yq[p]+=__shfl_xor(yq[p],8);
    yk[p]+=__shfl_xor(yk[p],8);
    yv[p]+=__shfl_xor(yv[p],8);
  }
  #pragma unroll
  for(int jj=0;jj<3;jj++){
    sq3[jj]+=__shfl_xor(sq3[jj],8);
    sk3[jj]+=__shfl_xor(sk3[jj],8);
    sv3[jj]+=__shfl_xor(sv3[jj],8);
  }

  const float scale = 0.3015113445777636f;  // 1/sqrt(11)
  size_t rb=((size_t)(b*8+o)*T_+t);
  if(ih==0){
    float4* qr=(float4*)(qp_+rb*12);
    qr[0]=make_float4(yq[0]*scale, yq[2]*scale, yq[3]*scale, yq[4]*scale);
    qr[1]=make_float4(yq[8]*scale, yq[9]*scale, yq[10]*scale, yq[14]*scale);
    qr[2]=make_float4(sq3[0]*scale, sq3[1]*scale, sq3[2]*scale, 0.f);
    float4* vr=(float4*)(vp_+rb*20);
    vr[0]=make_float4(yv[0],yv[1],yv[2],yv[3]);
    vr[1]=make_float4(yv[4],yv[5],yv[6],yv[7]);
    vr[2]=make_float4(yv[8],yv[9],yv[10],yv[11]);
  } else {
    float4* kr=(float4*)(kp_+rb*12);
    kr[0]=make_float4(yk[0],yk[2],yk[3],yk[4]);
    kr[1]=make_float4(yk[8],yk[9],yk[10],yk[14]);
    kr[2]=make_float4(sk3[0],sk3[1],sk3[2],0.f);
    float4* vr=(float4*)(vp_+rb*20);
    vr[3]=make_float4(yv[12],yv[13],yv[14],yv[15]);
    vr[4]=make_float4(sv3[0],sv3[1],sv3[2],0.f);
  }
}

// ---- K_B: attention, no-max softmax, balanced flash-split ----------------
// 256 thr = 32 q-threads x 8 key-lanes; 4 queries/thread (128-query strip).
// Direct-global K/V reads (no LDS, no barriers): per bh K+V = 256KB, L2-hot;
// 8 qi-lanes of a wave read the same key row -> L1 broadcast. R7 showed waves
// parked at staging barriers (VALU 42%, occ 16%); free-running waves hide
// latency with unroll-2 pipelining instead.
__global__ void __launch_bounds__(256,1) k_attn(
    const float* __restrict__ qp_, const float* __restrict__ kp_,
    const float* __restrict__ vp_,
    float* __restrict__ part)
{
  int tid=threadIdx.x; int qi=tid>>3, ki=tid&7;
  int j=blockIdx.x;
  int bh=j&15;
  int z=NSLOT-1-(j>>4);          // ascending slot id; j ordered heavy-first
  // decode z -> (strip s, split sp): c(s)=(s+2)>>1
  int s=0, bse=0;
  while (bse + ((s+2)>>1) <= z){ bse += (s+2)>>1; s++; }
  int sp = z - bse;
  int c  = (s+2)>>1;
  int ntiles = 2*(s+1);
  int t0 = sp*ntiles/c, t1 = (sp+1)*ntiles/c;
  int q0 = s*128;

  float qp[4][12];
  int kend[4];
  #pragma unroll
  for(int w=0;w<4;w++){
    int q=q0+qi+32*w;
    kend[w]=(q&~15)+16;
    const float4* p4=(const float4*)(qp_+((size_t)bh*T_+q)*12);
    #pragma unroll
    for(int i=0;i<3;i++){ float4 v=p4[i];
      qp[w][i*4]=v.x; qp[w][i*4+1]=v.y; qp[w][i*4+2]=v.z; qp[w][i*4+3]=v.w; }
  }

  float acc[4][20];
  #pragma unroll
  for(int w=0;w<4;w++)
    #pragma unroll
    for(int p=0;p<20;p++) acc[w][p]=0.f;

  const float4* gk=(const float4*)kp_ + (size_t)bh*T_*3;
  const float4* gv=(const float4*)vp_ + (size_t)bh*T_*5;

  for(int tile=t0; tile<t1; ++tile){
    int s0=tile*KB;
    #pragma unroll 2
    for(int it=0; it<8; ++it){
      int skey=s0+ki+it*8;
      const float4* K4=gk+(size_t)skey*3;
      const float4* V4=gv+(size_t)skey*5;
      float4 k0=K4[0],k1=K4[1],k2=K4[2];
      float4 v0=V4[0],v1=V4[1],v2=V4[2],v3=V4[3],v4=V4[4];
      float cc[4];
      #pragma unroll
      for(int w=0;w<4;w++){
        float d = qp[w][0]*k0.x+qp[w][1]*k0.y+qp[w][2]*k0.z+qp[w][3]*k0.w
                + qp[w][4]*k1.x+qp[w][5]*k1.y+qp[w][6]*k1.z+qp[w][7]*k1.w
                + qp[w][8]*k2.x+qp[w][9]*k2.y+qp[w][10]*k2.z;
        cc[w]=(skey<kend[w])? __expf(d) : 0.f;
      }
      #pragma unroll
      for(int w=0;w<4;w++){
        float cw=cc[w];
        acc[w][0]+=cw*v0.x; acc[w][1]+=cw*v0.y; acc[w][2]+=cw*v0.z; acc[w][3]+=cw*v0.w;
        acc[w][4]+=cw*v1.x; acc[w][5]+=cw*v1.y; acc[w][6]+=cw*v1.z; acc[w][7]+=cw*v1.w;
        acc[w][8]+=cw*v2.x; acc[w][9]+=cw*v2.y; acc[w][10]+=cw*v2.z; acc[w][11]+=cw*v2.w;
        acc[w][12]+=cw*v3.x; acc[w][13]+=cw*v3.y; acc[w][14]+=cw*v3.z; acc[w][15]+=cw*v3.w;
        acc[w][16]+=cw;
        acc[w][17]+=cw*v4.x; acc[w][18]+=cw*v4.y; acc[w][19]+=cw*v4.z;
      }
    }
  }

  // butterfly sum across 8 key-lanes (pure adds)
  #pragma unroll
  for(int mk=1; mk<8; mk<<=1){
    #pragma unroll
    for(int w=0;w<4;w++)
      #pragma unroll
      for(int p=0;p<20;p++) acc[w][p]+=__shfl_xor(acc[w][p],mk);
  }

  if(ki==0){
    #pragma unroll
    for(int w=0;w<4;w++){
      float* pr = part + ((size_t)(bh*NSLOT + z)*128 + qi + 32*w)*20;
      float4* p4=(float4*)pr;
      p4[0]=make_float4(acc[w][0],acc[w][1],acc[w][2],acc[w][3]);
      p4[1]=make_float4(acc[w][4],acc[w][5],acc[w][6],acc[w][7]);
      p4[2]=make_float4(acc[w][8],acc[w][9],acc[w][10],acc[w][11]);
      p4[3]=make_float4(acc[w][12],acc[w][13],acc[w][14],acc[w][15]);
      p4[4]=make_float4(acc[w][16],acc[w][17],acc[w][18],acc[w][19]);
    }
  }
}

// ---- K_C: combine partials + ao + norm + m1 + GP/join + m2 + out ---------
__global__ void __launch_bounds__(64) k_tail(
    const float* __restrict__ part,
    const float* __restrict__ w_ao_mv, const float* __restrict__ w_ao_s2mv,
    const float* __restrict__ w_ao_m2s, const float* __restrict__ w_ao_s2s,
    const float* __restrict__ b_ao_mv, const float* __restrict__ b_ao_s,
    const float* __restrict__ h_mv, const float* __restrict__ h_s,
    const float* __restrict__ w_m1_mv, const float* __restrict__ w_m1_s2mv,
    const float* __restrict__ w_m1_m2s, const float* __restrict__ w_m1_s2s,
    const float* __restrict__ b_m1_mv, const float* __restrict__ b_m1_s,
    const float* __restrict__ w_m2_mv, const float* __restrict__ w_m2_s2mv,
    const float* __restrict__ b_m2_mv,
    const float* __restrict__ w_out_mv,
    float* __restrict__ out)
{
  __shared__ int   GPI[256]; __shared__ float GPS[256];
  __shared__ int   JNI[256]; __shared__ float JNS[256];
  __shared__ float OS[4*152];
  __shared__ float NS[4*152];
  __shared__ float U[4*264];
  __shared__ float G[4*136];
  __shared__ float GSm[4*24];
  int tid=threadIdx.x, tl=tid>>4, ln=tid&15;
  int o=ln&7, ih=ln>>3;
  int tt=blockIdx.x*4+tl;

  { // build tables (threads 0..31)
    const int mask_of[16]={0,1,2,4,8,3,5,9,6,10,12,7,11,13,14,15};
    const int idx_of[16] ={0,1,2,5,3,6,8,11,4,7,9,12,10,13,14,15};
    if (tid<16){
      int k=tid, km=mask_of[k], slotn=0;
      for(int i=0;i<16;i++){
        int im=mask_of[i], jm=im^km;
        if(im & jm & 1) continue;
        GPI[k*16+slotn]=i|(idx_of[jm]<<4);
        GPS[k*16+slotn]=(float)rsign_d(im,jm);
        slotn++;
      }
      for(;slotn<16;slotn++){ GPI[k*16+slotn]=0; GPS[k*16+slotn]=0.f; }
    } else if (tid<32){
      int p=tid-16, pm=mask_of[p], rest=15&~pm, slotn=0;
      for(int u=0;u<16;u++){
        if(u & ~rest) continue;
        int am=pm|u, bm=pm|(rest&~u);
        float s=(float)( rsign_d(pm,15&~pm)*rsign_d(15&~am,15&~bm)
                        *rsign_d(am,15&~am)*rsign_d(bm,15&~bm) );
        JNI[p*16+slotn]=idx_of[am]|(idx_of[bm]<<4);
        JNS[p*16+slotn]=s;
        slotn++;
      }
      for(;slotn<16;slotn++){ JNI[p*16+slotn]=0; JNS[p*16+slotn]=0.f; }
    }
  }

  // combine attention partials: lane = (head h, comp-half)
  {
    int b=tt>>11, t=tt&(T_-1);
    int strip=t>>7, qi=t&127;
    int h=ln>>1, half=ln&1;
    int nsp=(strip+2)>>1;
    int kk=strip>>1;
    int rbase=(strip&1)? (kk+1)*(kk+1) : kk*kk+kk;
    const float* pb = part + ((size_t)((b*8+h)*NSLOT+rbase)*128 + qi)*20;
    float am[8]={0,0,0,0,0,0,0,0};
    float lv=0.f, s0=0.f, s1=0.f, s2=0.f;
    for(int spp=0; spp<nsp; ++spp){
      const float4* p4=(const float4*)(pb + (size_t)spp*128*20);
      float4 a=p4[half*2], b4=p4[half*2+1], meta=p4[4];
      am[0]+=a.x; am[1]+=a.y; am[2]+=a.z; am[3]+=a.w;
      am[4]+=b4.x; am[5]+=b4.y; am[6]+=b4.z; am[7]+=b4.w;
      lv+=meta.x; s0+=meta.y; s1+=meta.z; s2+=meta.w;
    }
    float inv=1.f/lv;
    float* os=&OS[tl*152];
    #pragma unroll
    for(int p=0;p<8;p++) os[h*16+half*8+p]=am[p]*inv;
    if(half==1){ os[128+h*3]=s0*inv; os[128+h*3+1]=s1*inv; os[128+h*3+2]=s2*inv; }
  }
  __syncthreads();

  const float* os=&OS[tl*152];
  float xh[4][16];
  #pragma unroll
  for(int ii=0;ii<4;ii++){
    #pragma unroll
    for(int p=0;p<16;p++) xh[ii][p]=os[(ih*4+ii)*16+p];
  }
  float xs[24];
  #pragma unroll
  for(int jj=0;jj<24;jj++) xs[jj]=os[128+jj];

  // ao: channel o, partial over i-half and j-half
  float y[16];
  #pragma unroll
  for(int p=0;p<16;p++) y[p]=0.f;
  #pragma unroll
  for(int ii=0;ii<4;ii++){
    const float* wi=w_ao_mv+o*72+(ih*4+ii)*9;
    #pragma unroll
    for(int p=0;p<16;p++){
      y[p]+=wi[GRADE[p]]*xh[ii][p];
      if(AUGK[p]>=0) y[p]+=wi[AUGK[p]]*xh[ii][AUGS[p]];
    }
  }
  float e=(ih==0)? b_ao_mv[o] : 0.f;
  for(int j2=ih*12;j2<ih*12+12;j2++) e+=w_ao_s2mv[o*24+j2]*xs[j2];
  y[0]+=e;
  float a3[3];
  #pragma unroll
  for(int jj=0;jj<3;jj++) a3[jj]=(ih==0)? b_ao_s[o*3+jj] : 0.f;
  #pragma unroll
  for(int ii=0;ii<4;ii++){
    #pragma unroll
    for(int jj=0;jj<3;jj++) a3[jj]+=w_ao_m2s[(o*3+jj)*8+(ih*4+ii)]*xh[ii][0];
  }
  for(int j2=ih*12;j2<ih*12+12;j2++){
    #pragma unroll
    for(int jj=0;jj<3;jj++) a3[jj]+=w_ao_s2s[(o*3+jj)*24+j2]*xs[j2];
  }
  #pragma unroll
  for(int p=0;p<16;p++) y[p]+=__shfl_xor(y[p],8);
  #pragma unroll
  for(int jj=0;jj<3;jj++) a3[jj]+=__shfl_xor(a3[jj],8);

  // residual + norms
  float hch[16]; float sqv=0.f;
  { const float4* hg=(const float4*)(h_mv+(size_t)tt*128+o*16);
    #pragma unroll
    for(int r4=0;r4<4;r4++){ float4 v=hg[r4];
      hch[r4*4]=v.x+y[r4*4]; hch[r4*4+1]=v.y+y[r4*4+1];
      hch[r4*4+2]=v.z+y[r4*4+2]; hch[r4*4+3]=v.w+y[r4*4+3]; } }
  #pragma unroll
  for(int p=0;p<16;p++) sqv+=FINNER[p]*hch[p]*hch[p];
  sqv+=__shfl_xor(sqv,1); sqv+=__shfl_xor(sqv,2); sqv+=__shfl_xor(sqv,4);
  float dmv=rsqrtf(sqv*0.125f+0.01f);
  float hs3[3]; float ssq=0.f;
  #pragma unroll
  for(int jj=0;jj<3;jj++){
    float v=h_s[(size_t)tt*24+o*3+jj]+a3[jj];
    hs3[jj]=v; ssq+=v*v;
  }
  ssq+=__shfl_xor(ssq,1); ssq+=__shfl_xor(ssq,2); ssq+=__shfl_xor(ssq,4);
  float dss=rsqrtf(ssq*(1.f/24.f)+0.01f);

  float* nsbuf=&NS[tl*152];
  if(ih==0){
    #pragma unroll
    for(int p=0;p<16;p++) nsbuf[o*16+p]=hch[p]*dmv;
    #pragma unroll
    for(int jj=0;jj<3;jj++) nsbuf[128+o*3+jj]=hs3[jj]*dss;
  }
  __syncthreads();

  // m1: lane = output channel ln=0..15
  float u[16];
  #pragma unroll
  for(int p=0;p<16;p++) u[p]=0.f;
  for(int i=0;i<8;i++){
    float xi[16];
    const float4* xs4=(const float4*)&nsbuf[i*16];
    #pragma unroll
    for(int r4=0;r4<4;r4++){ float4 v=xs4[r4]; xi[r4*4]=v.x; xi[r4*4+1]=v.y; xi[r4*4+2]=v.z; xi[r4*4+3]=v.w; }
    const float* wi=w_m1_mv+ln*72+i*9;
    #pragma unroll
    for(int p=0;p<16;p++){
      u[p]+=wi[GRADE[p]]*xi[p];
      if(AUGK[p]>=0) u[p]+=wi[AUGK[p]]*xi[AUGS[p]];
    }
  }
  float e1=b_m1_mv[ln];
  for(int j2=0;j2<24;j2++) e1+=w_m1_s2mv[ln*24+j2]*nsbuf[128+j2];
  u[0]+=e1;
  { float* uu=&U[tl*264];
    #pragma unroll
    for(int p=0;p<16;p++) uu[ln*16+p]=u[p]; }
  if(ih==0){
    float s3[3];
    #pragma unroll
    for(int jj=0;jj<3;jj++) s3[jj]=b_m1_s[o*3+jj];
    for(int j2=0;j2<24;j2++){
      float s=nsbuf[128+j2];
      #pragma unroll
      for(int jj=0;jj<3;jj++) s3[jj]+=w_m1_s2s[(o*3+jj)*24+j2]*s;
    }
    for(int i=0;i<8;i++){
      float x0=nsbuf[i*16];
      #pragma unroll
      for(int jj=0;jj<3;jj++) s3[jj]+=w_m1_m2s[(o*3+jj)*8+i]*x0;
    }
    #pragma unroll
    for(int jj=0;jj<3;jj++) GSm[tl*24+o*3+jj]=gelu_f(s3[jj]);
  }
  __syncthreads();

  // GP (o<4) / JOIN (o>=4): product o, component half ih
  { const int*   TI=(o<4)? GPI : JNI;
    const float* TS=(o<4)? GPS : JNS;
    const float* uu=&U[tl*264];
    const float* lft=&uu[((o<4)? o : (4+o))*16];
    const float* rgt=&uu[((o<4)? (4+o) : (8+o))*16];
    float* gg=&G[tl*136];
    #pragma unroll
    for(int kk=0;kk<8;kk++){
      int k=ih*8+kk;
      float accv=0.f;
      #pragma unroll
      for(int e2=0;e2<16;e2++){
        int ij=TI[k*16+e2]; float sg=TS[k*16+e2];
        accv += sg * lft[ij&15] * rgt[ij>>4];
      }
      gg[o*16+k]=accv;
    }
  }
  __syncthreads();
  if(ih==0){
    float* gg=&G[tl*136];
    float gt=gelu_f(gg[o*16]);
    #pragma unroll
    for(int p=0;p<16;p++) gg[o*16+p]*=gt;
  }
  __syncthreads();

  // m2: channel o, i-half + j-half, combine
  float y2[16];
  #pragma unroll
  for(int p=0;p<16;p++) y2[p]=0.f;
  #pragma unroll
  for(int ii=0;ii<4;ii++){
    float xi[16];
    const float4* gi=(const float4*)&G[tl*136+(ih*4+ii)*16];
    #pragma unroll
    for(int r4=0;r4<4;r4++){ float4 v=gi[r4]; xi[r4*4]=v.x; xi[r4*4+1]=v.y; xi[r4*4+2]=v.z; xi[r4*4+3]=v.w; }
    const float* wi=w_m2_mv+o*72+(ih*4+ii)*9;
    #pragma unroll
    for(int p=0;p<16;p++){
      y2[p]+=wi[GRADE[p]]*xi[p];
      if(AUGK[p]>=0) y2[p]+=wi[AUGK[p]]*xi[AUGS[p]];
    }
  }
  float e2=(ih==0)? b_m2_mv[o] : 0.f;
  for(int j2=ih*12;j2<ih*12+12;j2++) e2+=w_m2_s2mv[o*24+j2]*GSm[tl*24+j2];
  y2[0]+=e2;
  #pragma unroll
  for(int p=0;p<16;p++) y2[p]+=__shfl_xor(y2[p],8);

  float hf[16];
  #pragma unroll
  for(int p=0;p<16;p++) hf[p]=hch[p]+y2[p];

  const float* wout=w_out_mv+o*9;
  float c5 =wout[2]*hf[5] +wout[6]*hf[2];
  float c6 =wout[2]*hf[6] +wout[6]*hf[3];
  float c7 =wout[2]*hf[7] +wout[6]*hf[4];
  float c11=wout[3]*hf[11]+wout[7]*hf[8];
  float c12=wout[3]*hf[12]+wout[7]*hf[9];
  float c13=wout[3]*hf[13]+wout[7]*hf[10];
  float c14=wout[3]*hf[14];
  #pragma unroll
  for(int mk=1; mk<8; mk<<=1){
    c5+=__shfl_xor(c5,mk); c6+=__shfl_xor(c6,mk); c7+=__shfl_xor(c7,mk);
    c11+=__shfl_xor(c11,mk); c12+=__shfl_xor(c12,mk);
    c13+=__shfl_xor(c13,mk); c14+=__shfl_xor(c14,mk);
  }
  if(ln==0){
    float dd=c14;
    dd=(fabsf(dd)>0.001f)? dd : (dd>=0.f? 0.001f : -0.001f);
    float* op=out+(size_t)tt*6;
    op[0]=-c13/dd; op[1]=c12/dd; op[2]=-c11/dd;
    op[3]=2.f*c5; op[4]=2.f*c6; op[5]=2.f*c7;
  }
}

extern "C" void kernel_launch(void* const* d_in, const int* in_sizes, int n_in,
                              void* d_out, int out_size, void* d_ws, size_t ws_size,
                              hipStream_t stream)
{
  (void)in_sizes; (void)n_in; (void)out_size; (void)ws_size;
  const float* x         =(const float*)d_in[0];
  const float* w_in_mv   =(const float*)d_in[1];
  const float* b_in_mv   =(const float*)d_in[2];
  const float* w_in_m2s  =(const float*)d_in[3];
  const float* b_in_s    =(const float*)d_in[4];
  const float* w_qkv_mv  =(const float*)d_in[5];
  const float* w_qkv_s2mv=(const float*)d_in[6];
  const float* w_qkv_m2s =(const float*)d_in[7];
  const float* w_qkv_s2s =(const float*)d_in[8];
  const float* w_ao_mv   =(const float*)d_in[9];
  const float* w_ao_s2mv =(const float*)d_in[10];
  const float* w_ao_m2s  =(const float*)d_in[11];
  const float* w_ao_s2s  =(const float*)d_in[12];
  const float* b_ao_mv   =(const float*)d_in[13];
  const float* b_ao_s    =(const float*)d_in[14];
  const float* w_m1_mv   =(const float*)d_in[15];
  const float* w_m1_s2mv =(const float*)d_in[16];
  const float* w_m1_m2s  =(const float*)d_in[17];
  const float* w_m1_s2s  =(const float*)d_in[18];
  const float* b_m1_mv   =(const float*)d_in[19];
  const float* b_m1_s    =(const float*)d_in[20];
  const float* w_m2_mv   =(const float*)d_in[21];
  const float* w_m2_s2mv =(const float*)d_in[22];
  const float* b_m2_mv   =(const float*)d_in[25];
  const float* w_out_mv  =(const float*)d_in[27];
  float* outp=(float*)d_out;

  float* ws=(float*)d_ws;
  size_t off=0;
  float* h_mv = ws+off; off+=(size_t)BTOK*128;
  float* h_s  = ws+off; off+=(size_t)BTOK*24;
  float* qpk  = ws+off; off+=(size_t)16*T_*12;
  float* kpk  = ws+off; off+=(size_t)16*T_*12;
  float* vpk  = ws+off; off+=(size_t)16*T_*20;
  float* part = ws+off; off+=(size_t)16*NSLOT*128*20;

  k_in  <<<BTOK/4,64,0,stream>>>(x,w_in_mv,b_in_mv,w_in_m2s,b_in_s,
                                 w_qkv_mv,w_qkv_s2mv,w_qkv_m2s,w_qkv_s2s,
                                 h_mv,h_s,qpk,kpk,vpk);
  k_attn<<<16*NSLOT,256,0,stream>>>(qpk,kpk,vpk,part);
  k_tail<<<BTOK/4,64,0,stream>>>(part,
                                 w_ao_mv,w_ao_s2mv,w_ao_m2s,w_ao_s2s,b_ao_mv,b_ao_s,
                                 h_mv,h_s,
                                 w_m1_mv,w_m1_s2mv,w_m1_m2s,w_m1_s2s,b_m1_mv,b_m1_s,
                                 w_m2_mv,w_m2_s2mv,b_m2_mv,w_out_mv,outp);
}